// Round 4
// baseline (588.707 us; speedup 1.0000x reference)
//
#include <hip/hip_runtime.h>

#define B_ 8
#define C_ 256
#define H_ 96
#define W_ 160
#define ND 9            // displacements per axis
#define NDISP 81
#define PADL 4
#define CK 2            // channels per LDS chunk
#define NCHUNK (C_ / CK)            // 128
#define ROWF 168                    // padded in2 row: 4 + 160 + 4 floats
#define CFLOATS (W_ + ND * ROWF)    // 160 + 1512 = 1672 floats per channel
#define NTHR 384
#define TX 4
#define NXG (W_ / TX)               // 40
#define NCOMP (ND * NXG)            // 360 compute threads
#define NSLOT (CK * NXG + CK * ND * NXG)  // 80 + 720 = 800 float4 slots/chunk
#define SLOTK 3                     // ceil(800/384)

// NOTE: no min-waves arg — __launch_bounds__(384,4) capped VGPRs at 128 and
// spilled acc[] to scratch (R3: WRITE_SIZE 1.0 GB for a 40 MB output).
__global__ __launch_bounds__(NTHR) void corr_lds_kernel(
    const float* __restrict__ in1,
    const float* __restrict__ in2,
    float* __restrict__ out)
{
    __shared__ float lds[2][CK][CFLOATS];   // 26752 B -> 3+ blocks/CU

    const int tid = threadIdx.x;
    // XCD swizzle: grid 768 = 8 XCD-chunks of 96; XCD k gets batch b=k
    const int sw = (blockIdx.x & 7) * H_ + (blockIdx.x >> 3);
    const int b = sw / H_;
    const int y = sw % H_;

    // ---- one-time zero: x-pads of all rows; full zero for OOB rows (both bufs)
    for (int i = tid; i < 2 * CK * ND; i += NTHR) {
        const int bf = i / (CK * ND);
        const int c  = (i / ND) % CK;
        const int dy = i % ND;
        float* row = &lds[bf][c][W_ + dy * ROWF];
        const int yp = y + dy - PADL;
        if (yp < 0 || yp >= H_) {
            for (int j = 0; j < ROWF; ++j) row[j] = 0.f;
        } else {
            row[0] = row[1] = row[2] = row[3] = 0.f;
            row[ROWF - 4] = row[ROWF - 3] = row[ROWF - 2] = row[ROWF - 1] = 0.f;
        }
    }

    // ---- per-thread staging slots (static unroll; rule #20: no dyn idx)
    const int chs = H_ * W_;             // channel stride (floats)
    const float4* src[SLOTK];
    int dstoff[SLOTK];
    bool valid[SLOTK];
    #pragma unroll
    for (int k = 0; k < SLOTK; ++k) {
        const int s = tid + k * NTHR;
        if (s < NSLOT) {
            if (s < CK * NXG) {
                const int c = s / NXG, i = s % NXG;
                src[k] = (const float4*)(in1 + ((size_t)(b * C_ + c) * H_ + y) * W_ + i * 4);
                dstoff[k] = c * CFLOATS + i * 4;
                valid[k] = true;
            } else {
                const int s2 = s - CK * NXG;
                const int c = s2 / (ND * NXG);
                const int r = s2 % (ND * NXG);
                const int dy = r / NXG, i = r % NXG;
                const int yp = y + dy - PADL;
                const bool v = (yp >= 0 && yp < H_);
                src[k] = (const float4*)(in2 + ((size_t)(b * C_ + c) * H_ + (v ? yp : 0)) * W_ + i * 4);
                dstoff[k] = c * CFLOATS + W_ + dy * ROWF + 4 + i * 4;
                valid[k] = v;   // OOB rows stay zero; never restaged
            }
        } else {
            src[k] = (const float4*)in1;
            dstoff[k] = 0;
            valid[k] = false;
        }
    }

    // compute-thread coords
    const int dy_t = tid / NXG;          // 0..8 (tid < NCOMP)
    const int x0   = (tid % NXG) * TX;

    float acc[ND][TX];
    #pragma unroll
    for (int dx = 0; dx < ND; ++dx)
        #pragma unroll
        for (int j = 0; j < TX; ++j) acc[dx][j] = 0.f;

    const float4 z4 = make_float4(0.f, 0.f, 0.f, 0.f);
    float4 rg[SLOTK];

    // ---- prologue: stage chunk 0 into buffer 0
    #pragma unroll
    for (int k = 0; k < SLOTK; ++k) rg[k] = valid[k] ? src[k][0] : z4;
    #pragma unroll
    for (int k = 0; k < SLOTK; ++k)
        src[k] = (const float4*)((const float*)src[k] + CK * chs);
    #pragma unroll
    for (int k = 0; k < SLOTK; ++k)
        if (valid[k]) *(float4*)(&lds[0][0][0] + dstoff[k]) = rg[k];
    __syncthreads();

    // ---- main loop over channel chunks, double-buffered, 1 barrier/chunk
    for (int kc = 0; kc < NCHUNK; ++kc) {
        const bool has_next = (kc + 1) < NCHUNK;
        if (has_next) {
            #pragma unroll
            for (int k = 0; k < SLOTK; ++k) rg[k] = valid[k] ? src[k][0] : z4;
            #pragma unroll
            for (int k = 0; k < SLOTK; ++k)
                src[k] = (const float4*)((const float*)src[k] + CK * chs);
        }

        if (tid < NCOMP) {
            const float* base = &lds[kc & 1][0][0];
            #pragma unroll
            for (int c = 0; c < CK; ++c) {
                const float* cb = base + c * CFLOATS;
                const float* row = cb + W_ + dy_t * ROWF;
                float4 a4 = *(const float4*)(cb + x0);
                float4 w0 = *(const float4*)(row + x0);
                float4 w1 = *(const float4*)(row + x0 + 4);
                float4 w2 = *(const float4*)(row + x0 + 8);
                float a[TX] = {a4.x, a4.y, a4.z, a4.w};
                float w[12] = {w0.x, w0.y, w0.z, w0.w,
                               w1.x, w1.y, w1.z, w1.w,
                               w2.x, w2.y, w2.z, w2.w};
                #pragma unroll
                for (int dx = 0; dx < ND; ++dx)
                    #pragma unroll
                    for (int j = 0; j < TX; ++j)
                        acc[dx][j] += a[j] * w[dx + j];
            }
        }

        if (has_next) {
            float* dbase = &lds[(kc + 1) & 1][0][0];
            #pragma unroll
            for (int k = 0; k < SLOTK; ++k)
                if (valid[k]) *(float4*)(dbase + dstoff[k]) = rg[k];
            __syncthreads();
        }
    }

    // ---- epilogue: scaled store
    if (tid < NCOMP) {
        const float s = 1.0f / (float)C_;
        float* outp = out + ((size_t)(b * NDISP + dy_t * ND) * H_ + y) * W_ + x0;
        #pragma unroll
        for (int dx = 0; dx < ND; ++dx) {
            float4 o = make_float4(acc[dx][0] * s, acc[dx][1] * s,
                                   acc[dx][2] * s, acc[dx][3] * s);
            *(float4*)(outp + dx * chs) = o;
        }
    }
}

extern "C" void kernel_launch(void* const* d_in, const int* in_sizes, int n_in,
                              void* d_out, int out_size, void* d_ws, size_t ws_size,
                              hipStream_t stream) {
    const float* in1 = (const float*)d_in[0];
    const float* in2 = (const float*)d_in[1];
    float* out = (float*)d_out;

    const int grid = B_ * H_;   // 768
    corr_lds_kernel<<<grid, NTHR, 0, stream>>>(in1, in2, out);
}

// Round 5
// 179.477 us; speedup vs baseline: 3.2801x; 3.2801x over previous
//
#include <hip/hip_runtime.h>
#include <stdint.h>

#define B_ 8
#define C_ 256
#define H_ 96
#define W_ 160
#define ND 9
#define NDISP 81
#define YB 3                  // y rows per block
#define CK 2                  // channels per chunk
#define NCHUNK (C_ / CK)      // 128
#define TX 8
#define NXG (W_ / TX)         // 20
#define NTHR 576              // 9 waves
#define NCOMP (YB * ND * NXG) // 540 compute threads
#define ROWS_PER_CH 14        // 3 in1 rows + 11 in2 rows
#define NROWS (CK * ROWS_PER_CH)  // 28
#define ROWSTRIDE 164         // floats (656 B): rows start 4 banks apart
#define ROWBYTES 656
#define BUF_FLOATS 4608       // 18432 B per buffer (18 x 1024B DMA slots)
#define GUARD 4
#define CHSTEP (CK * H_ * W_) // global float step per chunk

typedef const __attribute__((address_space(1))) void GV;
typedef __attribute__((address_space(3))) void LV;
#define DMA16(g, l) __builtin_amdgcn_global_load_lds((GV*)(g), (LV*)(l), 16, 0, 0)

__global__ __launch_bounds__(NTHR, 2) void corr_dma_kernel(
    const float* __restrict__ in1,
    const float* __restrict__ in2,
    float* __restrict__ out)
{
    __shared__ float lds[GUARD + 2 * BUF_FLOATS];   // 36880 B, never zero-inited

    const int tid  = threadIdx.x;
    const int b    = blockIdx.x & 7;                // XCD swizzle: batch pinned to XCD
    const int y0   = (blockIdx.x >> 3) * YB;
    const int lane = tid & 63;
    const int wv   = tid >> 6;                      // 0..8

    // ---- per-lane DMA source for this thread's 2 slots (j = 2*wv + k)
    const float* gsrc0;
    const float* gsrc1;
    {
        #define SETUP_SRC(k, gs) {                                              \
            const int j  = 2 * wv + (k);                                        \
            const int O  = j * 1024 + lane * 16;   /* linear LDS byte off */    \
            const int R  = O / ROWBYTES;                                        \
            const int xb = O - R * ROWBYTES;                                    \
            const float* p;                                                     \
            if (R >= NROWS) {                                                   \
                p = in1 + (size_t)b * C_ * H_ * W_;  /* dummy, never read */    \
            } else {                                                            \
                const int ch = R / ROWS_PER_CH;                                 \
                const int r  = R - ch * ROWS_PER_CH;                            \
                int row; const float* basep;                                    \
                if (r < YB) { row = y0 + r; basep = in1; }                      \
                else {                                                          \
                    row = y0 + r - 7;            /* yp = y0 + (r-3) - 4 */      \
                    row = row < 0 ? 0 : (row >= H_ ? H_ - 1 : row);             \
                    basep = in2;                 /* OOB rows: garbage, unread */ \
                }                                                               \
                const int xo = (xb < 640) ? (xb >> 2) : 0;  /* pad -> dummy */  \
                p = basep + ((size_t)(b * C_ + ch) * H_ + row) * W_ + xo;       \
            }                                                                   \
            gs = p; }
        SETUP_SRC(0, gsrc0)
        SETUP_SRC(1, gsrc1)
        #undef SETUP_SRC
    }

    // ---- compute-thread coords
    const bool isComp = (tid < NCOMP);
    int ty = 0, dy = 0, xg = 0;
    if (isComp) {
        ty = tid / (ND * NXG);
        const int r2 = tid % (ND * NXG);
        dy = r2 / NXG;
        xg = r2 % NXG;
    }
    const int  ypRow = y0 + ty + dy - 4;
    const bool rowOk = isComp && (ypRow >= 0) && (ypRow < H_);
    const int  x0    = xg * TX;

    float acc[ND][TX];
    #pragma unroll
    for (int dx = 0; dx < ND; ++dx)
        #pragma unroll
        for (int j = 0; j < TX; ++j) acc[dx][j] = 0.f;

    // ---- prologue: DMA chunk 0 into buffer 0
    DMA16(gsrc0, &lds[GUARD + (2 * wv) * 256]);
    DMA16(gsrc1, &lds[GUARD + (2 * wv + 1) * 256]);
    gsrc0 += CHSTEP; gsrc1 += CHSTEP;

    // ---- main loop: dbuf, counted vmcnt, raw barriers (no full drains)
    for (int kc = 0; kc < NCHUNK; ++kc) {
        const int buf = kc & 1;
        if (kc + 1 < NCHUNK) {
            const int nb = GUARD + (buf ^ 1) * BUF_FLOATS;
            DMA16(gsrc0, &lds[nb + (2 * wv) * 256]);
            DMA16(gsrc1, &lds[nb + (2 * wv + 1) * 256]);
            gsrc0 += CHSTEP; gsrc1 += CHSTEP;
            asm volatile("s_waitcnt vmcnt(2)" ::: "memory");  // chunk kc landed
        } else {
            asm volatile("s_waitcnt vmcnt(0)" ::: "memory");
        }
        __builtin_amdgcn_s_barrier();
        asm volatile("" ::: "memory");
        __builtin_amdgcn_sched_barrier(0);   // no ds_read hoists above barrier

        if (rowOk) {
            const float* base = &lds[GUARD + buf * BUF_FLOATS];
            #pragma unroll
            for (int ch = 0; ch < CK; ++ch) {
                const float* arow = base + (ch * ROWS_PER_CH + ty) * ROWSTRIDE + x0;
                const float* wrow = base + (ch * ROWS_PER_CH + YB + ty + dy) * ROWSTRIDE + x0 - 4;
                float4 a0 = *(const float4*)(arow);
                float4 a1 = *(const float4*)(arow + 4);
                float4 w0 = *(const float4*)(wrow);
                float4 w1 = *(const float4*)(wrow + 4);
                float4 w2 = *(const float4*)(wrow + 8);
                float4 w3 = *(const float4*)(wrow + 12);
                if (xg == 0)       w0 = make_float4(0.f, 0.f, 0.f, 0.f); // left pad
                if (xg == NXG - 1) w3 = make_float4(0.f, 0.f, 0.f, 0.f); // right pad
                float a[TX] = {a0.x, a0.y, a0.z, a0.w, a1.x, a1.y, a1.z, a1.w};
                float w[16] = {w0.x, w0.y, w0.z, w0.w, w1.x, w1.y, w1.z, w1.w,
                               w2.x, w2.y, w2.z, w2.w, w3.x, w3.y, w3.z, w3.w};
                #pragma unroll
                for (int dx = 0; dx < ND; ++dx)
                    #pragma unroll
                    for (int j = 0; j < TX; ++j)
                        acc[dx][j] += a[j] * w[dx + j];
            }
        }

        asm volatile("" ::: "memory");
        __builtin_amdgcn_s_barrier();   // readers done before buf is overwritten
    }

    // ---- epilogue (OOB-dy threads store zeros: correct per zero-pad semantics)
    if (isComp) {
        const float s = 1.0f / (float)C_;
        float* outp = out + ((size_t)(b * NDISP + dy * ND) * H_ + (y0 + ty)) * W_ + x0;
        #pragma unroll
        for (int dx = 0; dx < ND; ++dx) {
            float4 o0 = make_float4(acc[dx][0] * s, acc[dx][1] * s,
                                    acc[dx][2] * s, acc[dx][3] * s);
            float4 o1 = make_float4(acc[dx][4] * s, acc[dx][5] * s,
                                    acc[dx][6] * s, acc[dx][7] * s);
            *(float4*)(outp + dx * (H_ * W_))     = o0;
            *(float4*)(outp + dx * (H_ * W_) + 4) = o1;
        }
    }
}

extern "C" void kernel_launch(void* const* d_in, const int* in_sizes, int n_in,
                              void* d_out, int out_size, void* d_ws, size_t ws_size,
                              hipStream_t stream) {
    const float* in1 = (const float*)d_in[0];
    const float* in2 = (const float*)d_in[1];
    float* out = (float*)d_out;

    const int grid = B_ * (H_ / YB);   // 256 blocks = 1 per CU
    corr_dma_kernel<<<grid, NTHR, 0, stream>>>(in1, in2, out);
}

// Round 6
// 171.945 us; speedup vs baseline: 3.4238x; 1.0438x over previous
//
#include <hip/hip_runtime.h>
#include <stdint.h>

#define B_ 8
#define C_ 256
#define H_ 96
#define W_ 160
#define ND 9
#define NDISP 81
#define YB 3                  // y rows per block
#define CK 2                  // channels per chunk
#define NCHUNK (C_ / CK)      // 128
#define TX 8
#define NXG (W_ / TX)         // 20
#define NTHR 576              // 9 waves
#define NCOMP (YB * ND * NXG) // 540 compute threads
#define ROWS_PER_CH 14        // 3 in1 rows + 11 in2 rows
#define NROWS (CK * ROWS_PER_CH)  // 28
#define ROWSTRIDE 164         // floats (656 B/row)
#define ROWBYTES 656
#define BUF_FLOATS 4608       // 18432 B per buffer = 18 x 1024B DMA slots
#define BUF_BYTES 18432       // = 9 * 2048 -> buffers 2048-aligned (swizzle-safe)
#define NBUF 4                // depth-3 prefetch
#define CHSTEP (CK * H_ * W_) // global float step per chunk

typedef const __attribute__((address_space(1))) void GV;
typedef __attribute__((address_space(3))) void LV;
#define DMA16(g, l) __builtin_amdgcn_global_load_lds((GV*)(g), (LV*)(l), 16, 0, 0)

// 16B-block XOR swizzle within 2KB windows: spreads the 32B-stride lane
// pattern (4 bank-start classes, 5-way) to <=2-way. Involution; preserves
// 16B alignment so every ds_read_b128 maps to one whole block.
__device__ __forceinline__ int swz(int o) { return o ^ (((o >> 9) & 3) << 4); }

__global__ __launch_bounds__(NTHR, 2) void corr_dma4_kernel(
    const float* __restrict__ in1,
    const float* __restrict__ in2,
    float* __restrict__ out)
{
    __shared__ float lds[NBUF * BUF_FLOATS];   // 73728 B, never zero-inited

    const int tid  = threadIdx.x;
    const int b    = blockIdx.x & 7;            // XCD swizzle: batch pinned to XCD
    const int y0   = (blockIdx.x >> 3) * YB;
    const int lane = tid & 63;
    const int wv   = tid >> 6;                  // 0..8

    // ---- per-lane DMA source (2 slots/wave). Dest is LINEAR; source is
    // pre-swizzled so LDS[O] holds logical data swz(O) (rule #21 / m173).
    const float* gsrc0;
    const float* gsrc1;
    {
        #define SETUP_SRC(k, gs) {                                              \
            const int O  = (2 * wv + (k)) * 1024 + lane * 16;                   \
            const int Os = swz(O);                                              \
            const int R  = Os / ROWBYTES;                                       \
            const int xb = Os - R * ROWBYTES;                                   \
            const float* p;                                                     \
            if (R >= NROWS) {                                                   \
                p = in1 + (size_t)b * C_ * H_ * W_;  /* dummy, never read */    \
            } else {                                                            \
                const int ch = R / ROWS_PER_CH;                                 \
                const int r  = R - ch * ROWS_PER_CH;                            \
                int row; const float* basep;                                    \
                if (r < YB) { row = y0 + r; basep = in1; }                      \
                else {                                                          \
                    row = y0 + r - 7;            /* yp = y0 + (r-3) - 4 */      \
                    row = row < 0 ? 0 : (row >= H_ ? H_ - 1 : row);             \
                    basep = in2;                 /* OOB rows: garbage, unread */ \
                }                                                               \
                const int xo = (xb < 640) ? (xb >> 2) : 0;  /* pad -> dummy */  \
                p = basep + ((size_t)(b * C_ + ch) * H_ + row) * W_ + xo;       \
            }                                                                   \
            gs = p; }
        SETUP_SRC(0, gsrc0)
        SETUP_SRC(1, gsrc1)
        #undef SETUP_SRC
    }

    // ---- compute-thread coords
    const bool isComp = (tid < NCOMP);
    int ty = 0, dy = 0, xg = 0;
    if (isComp) {
        ty = tid / (ND * NXG);
        const int r2 = tid % (ND * NXG);
        dy = r2 / NXG;
        xg = r2 % NXG;
    }
    const int  ypRow = y0 + ty + dy - 4;
    const bool rowOk = isComp && (ypRow >= 0) && (ypRow < H_);
    const int  x0    = xg * TX;

    // ---- per-thread swizzled read offsets (bytes, buffer-local), setup-once.
    // Indices below are compile-time (unrolled) -> registers (rule #20).
    int aof[CK][2], wof[CK][4];
    #pragma unroll
    for (int ch = 0; ch < CK; ++ch) {
        const int ab = ((ch * ROWS_PER_CH + ty) * ROWSTRIDE + x0) * 4;
        aof[ch][0] = swz(ab);
        aof[ch][1] = swz(ab + 16);
        const int wb = ((ch * ROWS_PER_CH + YB + ty + dy) * ROWSTRIDE + x0 - 4) * 4;
        // xg==0: w0 would underflow the buffer by 16B; clamp addr (data masked)
        wof[ch][0] = swz(xg == 0 ? wb + 16 : wb);
        wof[ch][1] = swz(wb + 16);
        wof[ch][2] = swz(wb + 32);
        wof[ch][3] = swz(wb + 48);
    }

    float acc[ND][TX];
    #pragma unroll
    for (int dx = 0; dx < ND; ++dx)
        #pragma unroll
        for (int j = 0; j < TX; ++j) acc[dx][j] = 0.f;

    #define ISSUE(SLOT) do {                                                  \
        DMA16(gsrc0, &lds[(SLOT) * BUF_FLOATS + (2 * wv) * 256]);             \
        DMA16(gsrc1, &lds[(SLOT) * BUF_FLOATS + (2 * wv + 1) * 256]);         \
        gsrc0 += CHSTEP; gsrc1 += CHSTEP;                                     \
    } while (0);

    #define COMPUTE(BUFC)                                                     \
    if (rowOk) {                                                              \
        const char* bb = (const char*)lds + (BUFC) * BUF_BYTES;               \
        _Pragma("unroll")                                                     \
        for (int ch = 0; ch < CK; ++ch) {                                     \
            float4 a0 = *(const float4*)(bb + aof[ch][0]);                    \
            float4 a1 = *(const float4*)(bb + aof[ch][1]);                    \
            float4 w0 = *(const float4*)(bb + wof[ch][0]);                    \
            float4 w1 = *(const float4*)(bb + wof[ch][1]);                    \
            float4 w2 = *(const float4*)(bb + wof[ch][2]);                    \
            float4 w3 = *(const float4*)(bb + wof[ch][3]);                    \
            if (xg == 0)       w0 = make_float4(0.f, 0.f, 0.f, 0.f);          \
            if (xg == NXG - 1) w3 = make_float4(0.f, 0.f, 0.f, 0.f);          \
            float a[TX] = {a0.x, a0.y, a0.z, a0.w, a1.x, a1.y, a1.z, a1.w};   \
            float w[16] = {w0.x, w0.y, w0.z, w0.w, w1.x, w1.y, w1.z, w1.w,    \
                           w2.x, w2.y, w2.z, w2.w, w3.x, w3.y, w3.z, w3.w};   \
            _Pragma("unroll")                                                 \
            for (int dx = 0; dx < ND; ++dx) {                                 \
                _Pragma("unroll")                                             \
                for (int j = 0; j < TX; ++j)                                  \
                    acc[dx][j] += a[j] * w[dx + j];                           \
            }                                                                 \
        }                                                                     \
    }

    // One barrier per chunk:
    //   wait own vmcnt  -> (barrier) all waves' DMAs for chunk kc landed AND
    //   all waves done computing kc-1 -> safe to issue kc+3 into slot (kc-1)&3
    #define BODY(BUFC, WN, DOISS)                                             \
        asm volatile("s_waitcnt vmcnt(" WN ")" ::: "memory");                 \
        __builtin_amdgcn_s_barrier();                                         \
        asm volatile("" ::: "memory");                                        \
        __builtin_amdgcn_sched_barrier(0);                                    \
        if (DOISS) { ISSUE(((BUFC) + 3) & 3) }                                \
        COMPUTE(BUFC)

    // ---- prologue: DMA chunks 0,1,2 into slots 0,1,2 (6 outstanding/wave)
    ISSUE(0)
    ISSUE(1)
    ISSUE(2)

    // ---- main loop: kc = 0..123, buffers cycle 0..3 (compile-time)
    #pragma unroll 1
    for (int g = 0; g < 31; ++g) {
        BODY(0, "4", true)
        BODY(1, "4", true)
        BODY(2, "4", true)
        BODY(3, "4", true)
    }
    // ---- tail: kc = 124..127
    BODY(0, "4", true)    // kc=124, issues chunk 127
    BODY(1, "4", false)   // kc=125 (3 chunks outstanding -> wait 4)
    BODY(2, "2", false)   // kc=126
    BODY(3, "0", false)   // kc=127

    #undef BODY
    #undef COMPUTE
    #undef ISSUE

    // ---- epilogue (OOB-dy threads store zeros: correct per zero-pad semantics)
    if (isComp) {
        const float s = 1.0f / (float)C_;
        float* outp = out + ((size_t)(b * NDISP + dy * ND) * H_ + (y0 + ty)) * W_ + x0;
        #pragma unroll
        for (int dx = 0; dx < ND; ++dx) {
            float4 o0 = make_float4(acc[dx][0] * s, acc[dx][1] * s,
                                    acc[dx][2] * s, acc[dx][3] * s);
            float4 o1 = make_float4(acc[dx][4] * s, acc[dx][5] * s,
                                    acc[dx][6] * s, acc[dx][7] * s);
            *(float4*)(outp + dx * (H_ * W_))     = o0;
            *(float4*)(outp + dx * (H_ * W_) + 4) = o1;
        }
    }
}

extern "C" void kernel_launch(void* const* d_in, const int* in_sizes, int n_in,
                              void* d_out, int out_size, void* d_ws, size_t ws_size,
                              hipStream_t stream) {
    const float* in1 = (const float*)d_in[0];
    const float* in2 = (const float*)d_in[1];
    float* out = (float*)d_out;

    const int grid = B_ * (H_ / YB);   // 256 blocks = 1 per CU
    corr_dma4_kernel<<<grid, NTHR, 0, stream>>>(in1, in2, out);
}